// Round 1
// baseline (782.889 us; speedup 1.0000x reference)
//
#include <hip/hip_runtime.h>
#include <math.h>

#define MAXDEG 64

// ---------------------------------------------------------------- adjacency
__global__ __launch_bounds__(256) void k_scatter(const int* __restrict__ src,
                                                 const int* __restrict__ dst,
                                                 int* __restrict__ cur,
                                                 int* __restrict__ col, int E) {
    int e = blockIdx.x * 256 + threadIdx.x;
    if (e >= E) return;
    int d = dst[e];
    int slot = atomicAdd(&cur[d], 1);
    if (slot < MAXDEG) col[d * MAXDEG + slot] = src[e];
}

__global__ __launch_bounds__(256) void k_invdeg(const int* __restrict__ cur,
                                                float* __restrict__ inv, int n) {
    int i = blockIdx.x * 256 + threadIdx.x;
    if (i < n) inv[i] = 1.0f / (float)(cur[i] > 1 ? cur[i] : 1);
}

__global__ __launch_bounds__(256) void k_x4(const float* __restrict__ value,
                                            const float* __restrict__ u,
                                            float4* __restrict__ x4, int n) {
    int i = blockIdx.x * 256 + threadIdx.x;
    if (i < n) x4[i] = make_float4(value[i], u[2 * i], u[2 * i + 1], 0.f);
}

// ---------------------------------------------------------------- layer 1: [N,3] -> [N,64]
__global__ __launch_bounds__(256) void k_l1(const float4* __restrict__ x4,
                                            const int* __restrict__ col,
                                            const int* __restrict__ degA,
                                            const float* __restrict__ inv,
                                            const float* __restrict__ W1,
                                            const float* __restrict__ b1,
                                            float* __restrict__ out, int nNodes) {
    const int lane = threadIdx.x & 63;
    const int n = blockIdx.x * 4 + (threadIdx.x >> 6);
    if (n >= nNodes) return;
    int deg = degA[n]; if (deg > MAXDEG) deg = MAXDEG;
    float a0 = 0.f, a1 = 0.f, a2 = 0.f;
    for (int j = lane; j < deg; j += 64) {
        float4 v = x4[col[n * MAXDEG + j]];
        a0 += v.x; a1 += v.y; a2 += v.z;
    }
#pragma unroll
    for (int o = 32; o; o >>= 1) {
        a0 += __shfl_xor(a0, o, 64);
        a1 += __shfl_xor(a1, o, 64);
        a2 += __shfl_xor(a2, o, 64);
    }
    float iv = inv[n];
    out[(size_t)n * 64 + lane] =
        b1[lane] + iv * (a0 * W1[lane] + a1 * W1[64 + lane] + a2 * W1[128 + lane]);
}

// ---------------------------------------------------------------- aggregation (wave per node)
template <int D>
__global__ __launch_bounds__(256) void k_agg(const float* __restrict__ H,
                                             const int* __restrict__ col,
                                             const int* __restrict__ degA,
                                             const float* __restrict__ inv,
                                             float* __restrict__ out, int nNodes) {
    const int lane = threadIdx.x & 63;
    const int n = blockIdx.x * 4 + (threadIdx.x >> 6);
    if (n >= nNodes) return;
    int deg = degA[n]; if (deg > MAXDEG) deg = MAXDEG;
    const int* cl = col + (size_t)n * MAXDEG;
    int myc = (lane < deg) ? cl[lane] : 0;
    float a0 = 0.f, a1 = 0.f;
    if (D == 128) {
        const float2* H2 = reinterpret_cast<const float2*>(H);
        int j = 0;
        for (; j + 2 <= deg; j += 2) {
            int s0 = __builtin_amdgcn_readlane(myc, j);
            int s1 = __builtin_amdgcn_readlane(myc, j + 1);
            float2 v0 = H2[(size_t)s0 * 64 + lane];
            float2 v1 = H2[(size_t)s1 * 64 + lane];
            a0 += v0.x + v1.x; a1 += v0.y + v1.y;
        }
        if (j < deg) {
            int s = __builtin_amdgcn_readlane(myc, j);
            float2 v = H2[(size_t)s * 64 + lane];
            a0 += v.x; a1 += v.y;
        }
        float iv = inv[n];
        reinterpret_cast<float2*>(out)[(size_t)n * 64 + lane] = make_float2(a0 * iv, a1 * iv);
    } else {  // D == 64
        int j = 0;
        for (; j + 2 <= deg; j += 2) {
            int s0 = __builtin_amdgcn_readlane(myc, j);
            int s1 = __builtin_amdgcn_readlane(myc, j + 1);
            a0 += H[(size_t)s0 * 64 + lane];
            a1 += H[(size_t)s1 * 64 + lane];
        }
        if (j < deg) {
            int s = __builtin_amdgcn_readlane(myc, j);
            a0 += H[(size_t)s * 64 + lane];
        }
        out[(size_t)n * 64 + lane] = (a0 + a1) * inv[n];
    }
}

// ---------------------------------------------------------------- activation
template <int ACT>
__device__ inline float actf(float x) {
    if (ACT == 1) return x > 0.f ? x : 0.01f * x;
    if (ACT == 2) return 1.f / (1.f + expf(-x));
    return x;
}

// ---------------------------------------------------------------- GEMM: [N,DIN] @ [DIN,128] + b, activation
// tile: 64 nodes x 128 cols, block 256, thread tile 8 nodes x 4 cols
template <int DIN, int ACT>
__global__ __launch_bounds__(256) void k_gemm(const float* __restrict__ A,
                                              const float* __restrict__ W,
                                              const float* __restrict__ B,
                                              float* __restrict__ Y, int nNodes) {
    __shared__ float As[64 * DIN];
    const int tid = threadIdx.x;
    const int tile = blockIdx.x * 64;

    // stage A tile (zero-padded past nNodes)
    const float4* A4 = reinterpret_cast<const float4*>(A);
    constexpr int C4 = DIN / 4;
#pragma unroll
    for (int k = 0; k < (64 * C4) / 256; ++k) {
        int idx = tid + k * 256;
        int row = idx / C4;
        int c4 = idx % C4;
        float4 v = make_float4(0.f, 0.f, 0.f, 0.f);
        int n = tile + row;
        if (n < nNodes) v = A4[(size_t)n * C4 + c4];
        *reinterpret_cast<float4*>(&As[row * DIN + c4 * 4]) = v;
    }
    __syncthreads();

    const int tcol = tid & 31;   // 4 cols: 4*tcol..4*tcol+3
    const int trow = tid >> 5;   // 8 nodes: trow*8..trow*8+7
    const float* Wp = W + tcol * 4;
    float acc[8][4] = {};

#pragma unroll 2
    for (int i = 0; i < DIN; i += 4) {
        const float4 w0 = *reinterpret_cast<const float4*>(Wp + (size_t)(i + 0) * 128);
        const float4 w1 = *reinterpret_cast<const float4*>(Wp + (size_t)(i + 1) * 128);
        const float4 w2 = *reinterpret_cast<const float4*>(Wp + (size_t)(i + 2) * 128);
        const float4 w3 = *reinterpret_cast<const float4*>(Wp + (size_t)(i + 3) * 128);
#pragma unroll
        for (int r = 0; r < 8; ++r) {
            const float4 a = *reinterpret_cast<const float4*>(&As[(trow * 8 + r) * DIN + i]);
            acc[r][0] = fmaf(a.x, w0.x, fmaf(a.y, w1.x, fmaf(a.z, w2.x, fmaf(a.w, w3.x, acc[r][0]))));
            acc[r][1] = fmaf(a.x, w0.y, fmaf(a.y, w1.y, fmaf(a.z, w2.y, fmaf(a.w, w3.y, acc[r][1]))));
            acc[r][2] = fmaf(a.x, w0.z, fmaf(a.y, w1.z, fmaf(a.z, w2.z, fmaf(a.w, w3.z, acc[r][2]))));
            acc[r][3] = fmaf(a.x, w0.w, fmaf(a.y, w1.w, fmaf(a.z, w2.w, fmaf(a.w, w3.w, acc[r][3]))));
        }
    }

    const float4 bias = *reinterpret_cast<const float4*>(B + tcol * 4);
#pragma unroll
    for (int r = 0; r < 8; ++r) {
        int n = tile + trow * 8 + r;
        if (n < nNodes) {
            float4 o;
            o.x = actf<ACT>(acc[r][0] + bias.x);
            o.y = actf<ACT>(acc[r][1] + bias.y);
            o.z = actf<ACT>(acc[r][2] + bias.z);
            o.w = actf<ACT>(acc[r][3] + bias.w);
            *reinterpret_cast<float4*>(&Y[(size_t)n * 128 + tcol * 4]) = o;
        }
    }
}

// ---------------------------------------------------------------- layer 10: fused gather + dot -> [N,1]
__global__ __launch_bounds__(256) void k_l10(const float* __restrict__ H,
                                             const int* __restrict__ col,
                                             const int* __restrict__ degA,
                                             const float* __restrict__ inv,
                                             const float* __restrict__ W,
                                             const float* __restrict__ B,
                                             float* __restrict__ out, int nNodes) {
    const int lane = threadIdx.x & 63;
    const int n = blockIdx.x * 4 + (threadIdx.x >> 6);
    if (n >= nNodes) return;
    int deg = degA[n]; if (deg > MAXDEG) deg = MAXDEG;
    const int* cl = col + (size_t)n * MAXDEG;
    int myc = (lane < deg) ? cl[lane] : 0;
    const float2* H2 = reinterpret_cast<const float2*>(H);
    float a0 = 0.f, a1 = 0.f;
    int j = 0;
    for (; j + 2 <= deg; j += 2) {
        int s0 = __builtin_amdgcn_readlane(myc, j);
        int s1 = __builtin_amdgcn_readlane(myc, j + 1);
        float2 v0 = H2[(size_t)s0 * 64 + lane];
        float2 v1 = H2[(size_t)s1 * 64 + lane];
        a0 += v0.x + v1.x; a1 += v0.y + v1.y;
    }
    if (j < deg) {
        int s = __builtin_amdgcn_readlane(myc, j);
        float2 v = H2[(size_t)s * 64 + lane];
        a0 += v.x; a1 += v.y;
    }
    float y = (a0 * W[2 * lane] + a1 * W[2 * lane + 1]) * inv[n];
#pragma unroll
    for (int o = 32; o; o >>= 1) y += __shfl_xor(y, o, 64);
    if (lane == 0) out[n] = y + B[0];
}

// ---------------------------------------------------------------- host
extern "C" void kernel_launch(void* const* d_in, const int* in_sizes, int n_in,
                              void* d_out, int out_size, void* d_ws, size_t ws_size,
                              hipStream_t stream) {
    const float* value = (const float*)d_in[0];
    const float* u = (const float*)d_in[1];
    const int* src = (const int*)d_in[2];
    const int* dst = (const int*)d_in[3];
    const float* W[10];
    const float* b[10];
    for (int i = 0; i < 10; ++i) {
        W[i] = (const float*)d_in[4 + 2 * i];
        b[i] = (const float*)d_in[5 + 2 * i];
    }
    const int N = in_sizes[0];
    const int E = in_sizes[2];
    float* out = (float*)d_out;

    char* p = (char*)d_ws;
    auto carve = [&](size_t bytes) {
        char* r = p;
        p += (bytes + 255) & ~(size_t)255;
        return r;
    };
    int* cur = (int*)carve((size_t)N * 4);
    int* col = (int*)carve((size_t)N * MAXDEG * 4);
    float* inv = (float*)carve((size_t)N * 4);
    float4* x4 = (float4*)carve((size_t)N * 16);
    float* agg = (float*)carve((size_t)N * 128 * 4);
    float* hA = (float*)carve((size_t)N * 128 * 4);
    float* hB = (float*)carve((size_t)N * 128 * 4);

    hipMemsetAsync(cur, 0, (size_t)N * 4, stream);
    k_scatter<<<(E + 255) / 256, 256, 0, stream>>>(src, dst, cur, col, E);
    k_invdeg<<<(N + 255) / 256, 256, 0, stream>>>(cur, inv, N);
    k_x4<<<(N + 255) / 256, 256, 0, stream>>>(value, u, x4, N);

    const int gw = (N + 3) / 4;
    const int gg = (N + 63) / 64;

    // L1: [N,3] -> [N,64] (no act)
    k_l1<<<gw, 256, 0, stream>>>(x4, col, cur, inv, W[0], b[0], hA, N);
    // L2: 64 -> 128, lrelu
    k_agg<64><<<gw, 256, 0, stream>>>(hA, col, cur, inv, agg, N);
    k_gemm<64, 1><<<gg, 256, 0, stream>>>(agg, W[1], b[1], hB, N);
    // L3: 128 -> 128, lrelu
    k_agg<128><<<gw, 256, 0, stream>>>(hB, col, cur, inv, agg, N);
    k_gemm<128, 1><<<gg, 256, 0, stream>>>(agg, W[2], b[2], hA, N);
    // L4: lrelu
    k_agg<128><<<gw, 256, 0, stream>>>(hA, col, cur, inv, agg, N);
    k_gemm<128, 1><<<gg, 256, 0, stream>>>(agg, W[3], b[3], hB, N);
    // L5: none
    k_agg<128><<<gw, 256, 0, stream>>>(hB, col, cur, inv, agg, N);
    k_gemm<128, 0><<<gg, 256, 0, stream>>>(agg, W[4], b[4], hA, N);
    // L6: none
    k_agg<128><<<gw, 256, 0, stream>>>(hA, col, cur, inv, agg, N);
    k_gemm<128, 0><<<gg, 256, 0, stream>>>(agg, W[5], b[5], hB, N);
    // L7: none
    k_agg<128><<<gw, 256, 0, stream>>>(hB, col, cur, inv, agg, N);
    k_gemm<128, 0><<<gg, 256, 0, stream>>>(agg, W[6], b[6], hA, N);
    // L8: none
    k_agg<128><<<gw, 256, 0, stream>>>(hA, col, cur, inv, agg, N);
    k_gemm<128, 0><<<gg, 256, 0, stream>>>(agg, W[7], b[7], hB, N);
    // L9: sigmoid
    k_agg<128><<<gw, 256, 0, stream>>>(hB, col, cur, inv, agg, N);
    k_gemm<128, 2><<<gg, 256, 0, stream>>>(agg, W[8], b[8], hA, N);
    // L10: 128 -> 1
    k_l10<<<gw, 256, 0, stream>>>(hA, col, cur, inv, W[9], b[9], out, N);
}

// Round 2
// 575.474 us; speedup vs baseline: 1.3604x; 1.3604x over previous
//
#include <hip/hip_runtime.h>
#include <math.h>

#define MAXDEG 64
typedef unsigned int uint32;
typedef unsigned short ushort16;

__device__ inline float bf_lo(uint32 v) { return __uint_as_float(v << 16); }
__device__ inline float bf_hi(uint32 v) { return __uint_as_float(v & 0xFFFF0000u); }
__device__ inline ushort16 f2bf(float f) {
    uint32 u = __float_as_uint(f);
    return (ushort16)((u + 0x7FFFu + ((u >> 16) & 1u)) >> 16);
}

// ---------------------------------------------------------------- adjacency
__global__ __launch_bounds__(256) void k_scatter(const int* __restrict__ src,
                                                 const int* __restrict__ dst,
                                                 int* __restrict__ cur,
                                                 int* __restrict__ col, int E) {
    int e = blockIdx.x * 256 + threadIdx.x;
    if (e >= E) return;
    int d = dst[e];
    int slot = atomicAdd(&cur[d], 1);
    if (slot < MAXDEG) col[d * MAXDEG + slot] = src[e];
}

__global__ __launch_bounds__(256) void k_invdeg(const int* __restrict__ cur,
                                                float* __restrict__ inv, int n) {
    int i = blockIdx.x * 256 + threadIdx.x;
    if (i < n) inv[i] = 1.0f / (float)(cur[i] > 1 ? cur[i] : 1);
}

__global__ __launch_bounds__(256) void k_x4(const float* __restrict__ value,
                                            const float* __restrict__ u,
                                            float4* __restrict__ x4, int n) {
    int i = blockIdx.x * 256 + threadIdx.x;
    if (i < n) x4[i] = make_float4(value[i], u[2 * i], u[2 * i + 1], 0.f);
}

// ---------------------------------------------------------------- layer 1: [N,3] -> [N,64] bf16 out
__global__ __launch_bounds__(256) void k_l1(const float4* __restrict__ x4,
                                            const int* __restrict__ col,
                                            const int* __restrict__ degA,
                                            const float* __restrict__ inv,
                                            const float* __restrict__ W1,
                                            const float* __restrict__ b1,
                                            ushort16* __restrict__ out, int nNodes) {
    const int lane = threadIdx.x & 63;
    const int n = blockIdx.x * 4 + (threadIdx.x >> 6);
    if (n >= nNodes) return;
    int deg = degA[n]; if (deg > MAXDEG) deg = MAXDEG;
    float a0 = 0.f, a1 = 0.f, a2 = 0.f;
    for (int j = lane; j < deg; j += 64) {
        float4 v = x4[col[n * MAXDEG + j]];
        a0 += v.x; a1 += v.y; a2 += v.z;
    }
#pragma unroll
    for (int o = 32; o; o >>= 1) {
        a0 += __shfl_xor(a0, o, 64);
        a1 += __shfl_xor(a1, o, 64);
        a2 += __shfl_xor(a2, o, 64);
    }
    float iv = inv[n];
    float y = b1[lane] + iv * (a0 * W1[lane] + a1 * W1[64 + lane] + a2 * W1[128 + lane]);
    out[(size_t)n * 64 + lane] = f2bf(y);
}

// ---------------------------------------------------------------- agg over bf16 rows, 128-wide
__global__ __launch_bounds__(256) void k_agg128h(const uint32* __restrict__ H32,
                                                 const int* __restrict__ col,
                                                 const int* __restrict__ degA,
                                                 const float* __restrict__ inv,
                                                 float2* __restrict__ out, int nNodes) {
    const int lane = threadIdx.x & 63;
    const int n = blockIdx.x * 4 + (threadIdx.x >> 6);
    if (n >= nNodes) return;
    int deg = degA[n]; if (deg > MAXDEG) deg = MAXDEG;
    const int* cl = col + (size_t)n * MAXDEG;
    int myc = (lane < deg) ? cl[lane] : 0;
    float a0 = 0.f, a1 = 0.f, b0 = 0.f, b1 = 0.f;
    int j = 0;
    for (; j + 4 <= deg; j += 4) {
        int s0 = __builtin_amdgcn_readlane(myc, j);
        int s1 = __builtin_amdgcn_readlane(myc, j + 1);
        int s2 = __builtin_amdgcn_readlane(myc, j + 2);
        int s3 = __builtin_amdgcn_readlane(myc, j + 3);
        uint32 v0 = H32[(size_t)s0 * 64 + lane];
        uint32 v1 = H32[(size_t)s1 * 64 + lane];
        uint32 v2 = H32[(size_t)s2 * 64 + lane];
        uint32 v3 = H32[(size_t)s3 * 64 + lane];
        a0 += bf_lo(v0) + bf_lo(v1);
        a1 += bf_hi(v0) + bf_hi(v1);
        b0 += bf_lo(v2) + bf_lo(v3);
        b1 += bf_hi(v2) + bf_hi(v3);
    }
    for (; j < deg; ++j) {
        int s = __builtin_amdgcn_readlane(myc, j);
        uint32 v = H32[(size_t)s * 64 + lane];
        a0 += bf_lo(v);
        a1 += bf_hi(v);
    }
    float iv = inv[n];
    out[(size_t)n * 64 + lane] = make_float2((a0 + b0) * iv, (a1 + b1) * iv);
}

// ---------------------------------------------------------------- agg over bf16 rows, 64-wide
__global__ __launch_bounds__(256) void k_agg64h(const ushort16* __restrict__ H16,
                                                const int* __restrict__ col,
                                                const int* __restrict__ degA,
                                                const float* __restrict__ inv,
                                                float* __restrict__ out, int nNodes) {
    const int lane = threadIdx.x & 63;
    const int n = blockIdx.x * 4 + (threadIdx.x >> 6);
    if (n >= nNodes) return;
    int deg = degA[n]; if (deg > MAXDEG) deg = MAXDEG;
    const int* cl = col + (size_t)n * MAXDEG;
    int myc = (lane < deg) ? cl[lane] : 0;
    float a0 = 0.f, a1 = 0.f, b0 = 0.f, b1 = 0.f;
    int j = 0;
    for (; j + 4 <= deg; j += 4) {
        int s0 = __builtin_amdgcn_readlane(myc, j);
        int s1 = __builtin_amdgcn_readlane(myc, j + 1);
        int s2 = __builtin_amdgcn_readlane(myc, j + 2);
        int s3 = __builtin_amdgcn_readlane(myc, j + 3);
        a0 += __uint_as_float((uint32)H16[(size_t)s0 * 64 + lane] << 16);
        a1 += __uint_as_float((uint32)H16[(size_t)s1 * 64 + lane] << 16);
        b0 += __uint_as_float((uint32)H16[(size_t)s2 * 64 + lane] << 16);
        b1 += __uint_as_float((uint32)H16[(size_t)s3 * 64 + lane] << 16);
    }
    for (; j < deg; ++j) {
        int s = __builtin_amdgcn_readlane(myc, j);
        a0 += __uint_as_float((uint32)H16[(size_t)s * 64 + lane] << 16);
    }
    out[(size_t)n * 64 + lane] = (a0 + a1 + b0 + b1) * inv[n];
}

// ---------------------------------------------------------------- activation
template <int ACT>
__device__ inline float actf(float x) {
    if (ACT == 1) return x > 0.f ? x : 0.01f * x;
    if (ACT == 2) return 1.f / (1.f + expf(-x));
    return x;
}

// ---------------------------------------------------------------- GEMM: fp32 [N,DIN] @ [DIN,128] + b -> bf16
template <int DIN, int ACT>
__global__ __launch_bounds__(256) void k_gemm(const float* __restrict__ A,
                                              const float* __restrict__ W,
                                              const float* __restrict__ B,
                                              ushort16* __restrict__ Y, int nNodes) {
    __shared__ float As[64 * DIN];
    const int tid = threadIdx.x;
    const int tile = blockIdx.x * 64;

    const float4* A4 = reinterpret_cast<const float4*>(A);
    constexpr int C4 = DIN / 4;
#pragma unroll
    for (int k = 0; k < (64 * C4) / 256; ++k) {
        int idx = tid + k * 256;
        int row = idx / C4;
        int c4 = idx % C4;
        float4 v = make_float4(0.f, 0.f, 0.f, 0.f);
        int n = tile + row;
        if (n < nNodes) v = A4[(size_t)n * C4 + c4];
        *reinterpret_cast<float4*>(&As[row * DIN + c4 * 4]) = v;
    }
    __syncthreads();

    const int tcol = tid & 31;
    const int trow = tid >> 5;
    const float* Wp = W + tcol * 4;
    float acc[8][4] = {};

#pragma unroll 2
    for (int i = 0; i < DIN; i += 4) {
        const float4 w0 = *reinterpret_cast<const float4*>(Wp + (size_t)(i + 0) * 128);
        const float4 w1 = *reinterpret_cast<const float4*>(Wp + (size_t)(i + 1) * 128);
        const float4 w2 = *reinterpret_cast<const float4*>(Wp + (size_t)(i + 2) * 128);
        const float4 w3 = *reinterpret_cast<const float4*>(Wp + (size_t)(i + 3) * 128);
#pragma unroll
        for (int r = 0; r < 8; ++r) {
            const float4 a = *reinterpret_cast<const float4*>(&As[(trow * 8 + r) * DIN + i]);
            acc[r][0] = fmaf(a.x, w0.x, fmaf(a.y, w1.x, fmaf(a.z, w2.x, fmaf(a.w, w3.x, acc[r][0]))));
            acc[r][1] = fmaf(a.x, w0.y, fmaf(a.y, w1.y, fmaf(a.z, w2.y, fmaf(a.w, w3.y, acc[r][1]))));
            acc[r][2] = fmaf(a.x, w0.z, fmaf(a.y, w1.z, fmaf(a.z, w2.z, fmaf(a.w, w3.z, acc[r][2]))));
            acc[r][3] = fmaf(a.x, w0.w, fmaf(a.y, w1.w, fmaf(a.z, w2.w, fmaf(a.w, w3.w, acc[r][3]))));
        }
    }

    const float4 bias = *reinterpret_cast<const float4*>(B + tcol * 4);
#pragma unroll
    for (int r = 0; r < 8; ++r) {
        int n = tile + trow * 8 + r;
        if (n < nNodes) {
            ushort4 o;
            o.x = f2bf(actf<ACT>(acc[r][0] + bias.x));
            o.y = f2bf(actf<ACT>(acc[r][1] + bias.y));
            o.z = f2bf(actf<ACT>(acc[r][2] + bias.z));
            o.w = f2bf(actf<ACT>(acc[r][3] + bias.w));
            *reinterpret_cast<ushort4*>(&Y[(size_t)n * 128 + tcol * 4]) = o;
        }
    }
}

// ---------------------------------------------------------------- layer 10 part 1: t = h @ W10  (128 -> 1)
__global__ __launch_bounds__(256) void k_dot10(const uint32* __restrict__ H32,
                                               const float* __restrict__ W,
                                               float* __restrict__ t, int nNodes) {
    const int lane = threadIdx.x & 63;
    const int n = blockIdx.x * 4 + (threadIdx.x >> 6);
    if (n >= nNodes) return;
    uint32 v = H32[(size_t)n * 64 + lane];
    float2 w = reinterpret_cast<const float2*>(W)[lane];
    float y = bf_lo(v) * w.x + bf_hi(v) * w.y;
#pragma unroll
    for (int o = 32; o; o >>= 1) y += __shfl_xor(y, o, 64);
    if (lane == 0) t[n] = y;
}

// ---------------------------------------------------------------- layer 10 part 2: out = inv * sum(t[src]) + b10
__global__ __launch_bounds__(256) void k_aggs(const float* __restrict__ t,
                                              const int* __restrict__ col,
                                              const int* __restrict__ degA,
                                              const float* __restrict__ inv,
                                              const float* __restrict__ B,
                                              float* __restrict__ out, int nNodes) {
    int n = blockIdx.x * 256 + threadIdx.x;
    if (n >= nNodes) return;
    int deg = degA[n]; if (deg > MAXDEG) deg = MAXDEG;
    const int* cl = col + (size_t)n * MAXDEG;
    float s = 0.f;
    for (int j = 0; j < deg; ++j) s += t[cl[j]];
    out[n] = s * inv[n] + B[0];
}

// ---------------------------------------------------------------- host
extern "C" void kernel_launch(void* const* d_in, const int* in_sizes, int n_in,
                              void* d_out, int out_size, void* d_ws, size_t ws_size,
                              hipStream_t stream) {
    const float* value = (const float*)d_in[0];
    const float* u = (const float*)d_in[1];
    const int* src = (const int*)d_in[2];
    const int* dst = (const int*)d_in[3];
    const float* W[10];
    const float* b[10];
    for (int i = 0; i < 10; ++i) {
        W[i] = (const float*)d_in[4 + 2 * i];
        b[i] = (const float*)d_in[5 + 2 * i];
    }
    const int N = in_sizes[0];
    const int E = in_sizes[2];
    float* out = (float*)d_out;

    char* p = (char*)d_ws;
    auto carve = [&](size_t bytes) {
        char* r = p;
        p += (bytes + 255) & ~(size_t)255;
        return r;
    };
    int* cur = (int*)carve((size_t)N * 4);
    int* col = (int*)carve((size_t)N * MAXDEG * 4);
    float* inv = (float*)carve((size_t)N * 4);
    float4* x4 = (float4*)carve((size_t)N * 16);
    float* agg = (float*)carve((size_t)N * 128 * 4);
    ushort16* hA = (ushort16*)carve((size_t)N * 128 * 2);
    ushort16* hB = (ushort16*)carve((size_t)N * 128 * 2);
    float* t10 = (float*)carve((size_t)N * 4);

    hipMemsetAsync(cur, 0, (size_t)N * 4, stream);
    k_scatter<<<(E + 255) / 256, 256, 0, stream>>>(src, dst, cur, col, E);
    k_invdeg<<<(N + 255) / 256, 256, 0, stream>>>(cur, inv, N);
    k_x4<<<(N + 255) / 256, 256, 0, stream>>>(value, u, x4, N);

    const int gw = (N + 3) / 4;
    const int gg = (N + 63) / 64;
    const int gt = (N + 255) / 256;

    // L1: [N,3] -> [N,64] bf16
    k_l1<<<gw, 256, 0, stream>>>(x4, col, cur, inv, W[0], b[0], hA, N);
    // L2: 64 -> 128, lrelu
    k_agg64h<<<gw, 256, 0, stream>>>(hA, col, cur, inv, agg, N);
    k_gemm<64, 1><<<gg, 256, 0, stream>>>(agg, W[1], b[1], hB, N);
    // L3
    k_agg128h<<<gw, 256, 0, stream>>>((const uint32*)hB, col, cur, inv, (float2*)agg, N);
    k_gemm<128, 1><<<gg, 256, 0, stream>>>(agg, W[2], b[2], hA, N);
    // L4
    k_agg128h<<<gw, 256, 0, stream>>>((const uint32*)hA, col, cur, inv, (float2*)agg, N);
    k_gemm<128, 1><<<gg, 256, 0, stream>>>(agg, W[3], b[3], hB, N);
    // L5
    k_agg128h<<<gw, 256, 0, stream>>>((const uint32*)hB, col, cur, inv, (float2*)agg, N);
    k_gemm<128, 0><<<gg, 256, 0, stream>>>(agg, W[4], b[4], hA, N);
    // L6
    k_agg128h<<<gw, 256, 0, stream>>>((const uint32*)hA, col, cur, inv, (float2*)agg, N);
    k_gemm<128, 0><<<gg, 256, 0, stream>>>(agg, W[5], b[5], hB, N);
    // L7
    k_agg128h<<<gw, 256, 0, stream>>>((const uint32*)hB, col, cur, inv, (float2*)agg, N);
    k_gemm<128, 0><<<gg, 256, 0, stream>>>(agg, W[6], b[6], hA, N);
    // L8
    k_agg128h<<<gw, 256, 0, stream>>>((const uint32*)hA, col, cur, inv, (float2*)agg, N);
    k_gemm<128, 0><<<gg, 256, 0, stream>>>(agg, W[7], b[7], hB, N);
    // L9: sigmoid
    k_agg128h<<<gw, 256, 0, stream>>>((const uint32*)hB, col, cur, inv, (float2*)agg, N);
    k_gemm<128, 2><<<gg, 256, 0, stream>>>(agg, W[8], b[8], hA, N);
    // L10: t = h@W10, then scalar aggregate
    k_dot10<<<gw, 256, 0, stream>>>((const uint32*)hA, W[9], t10, N);
    k_aggs<<<gt, 256, 0, stream>>>(t10, col, cur, inv, b[9], out, N);
}